// Round 1
// baseline (154.801 us; speedup 1.0000x reference)
//
#include <hip/hip_runtime.h>
#include <math.h>

#define B_    4
#define C_    19
#define H_    320
#define W_    320
#define HW_   (H_*W_)
#define CHW_  (C_*HW_)
#define NPIX_ (B_*HW_)
#define NEPS_ 256
#define BIGI_ (1<<20)
#define INF_  0x3fffffff
#define IGN_  255

// Compile-time exact replica of the reference eps chain: e0=1e-5f, e_{k+1}=e_k*1.2f
struct EpsTab { float v[NEPS_]; };
static constexpr EpsTab make_eps() {
  EpsTab t{}; float e = 1e-5f;
  for (int k = 0; k < NEPS_; ++k) { t.v[k] = e; e = e * 1.2f; }
  return t;
}
__device__ __constant__ EpsTab EPS = make_eps();

// ---------------- reduction helper (nw full waves) ---------------------------
__device__ __forceinline__ void block_reduce_add_w(float v, float* out, int nw) {
  #pragma unroll
  for (int o = 32; o > 0; o >>= 1) v += __shfl_down(v, o);
  __shared__ float shr[8];
  int lane = threadIdx.x & 63, wid = threadIdx.x >> 6;
  if (lane == 0) shr[wid] = v;
  __syncthreads();
  if (threadIdx.x == 0) {
    float s = 0.f;
    for (int w = 0; w < nw; ++w) s += shr[w];
    atomicAdd(out, s);
  }
}

__device__ __forceinline__ int eps_bin(float kl, const float* et) {
  // #{k : e_k < kl}, log2 guess + exact correction (identical compares to ref)
  if (!(kl > 1e-5f)) return 0;
  int g = (int)((__log2f(kl) + 16.6096404f) * 3.8017840f);
  g = min(max(g, 0), NEPS_ - 1);
  while (g < NEPS_ && et[g] < kl) ++g;
  while (g > 0 && !(et[g - 1] < kl)) --g;
  return g;
}

// ---------------- K1: one block per (b, row-pair): rowdt + softmax/KL -------
// Restructured vs prior version:
//  * dual row-DT min-scans via wave shuffles + one cross-wave LDS combine
//    (1 barrier instead of 18)
//  * single fused channel loop with scalar accumulators (no float[19] register
//    arrays): right-neighbor logits re-loaded at +1 (same cache line, L1-hit),
//    neighbor logZ recomputed as log(sum(exp(x_right))) -- bitwise identical
//    to the neighbor's own accumulation (same values, same order, same
//    intrinsics), removing all cross-lane/LDS boundary patches.
//  * boundary flags from shifted coalesced target loads (no tg LDS, no barrier)
// slices traffic: unchanged 3 rows per block (1.5 passes total).
__global__ __launch_bounds__(320) void k_front(const float* __restrict__ sl, const int* __restrict__ tgt,
                                               int* __restrict__ R, float* __restrict__ logZ,
                                               float* __restrict__ S, float* __restrict__ kl_map,
                                               int* __restrict__ hist, float* __restrict__ out) {
  int bid = blockIdx.x;
  int b = bid / (H_ / 2), ip = bid % (H_ / 2);
  int i0 = 2 * ip, i1 = i0 + 1, j = threadIdx.x;
  int lane = j & 63, wv = j >> 6;            // 5 waves
  bool hd1 = (i1 < H_ - 1);                  // row 2i+2 exists
  __shared__ float et[NEPS_];
  __shared__ int sh[257];
  __shared__ int wtot[4][5];                 // per-wave scan totals: a0,c0,a1,c1
  for (int e = j; e < 257; e += 320) sh[e] = 0;
  if (j < NEPS_) et[j] = EPS.v[j];

  // ---- targets + boundary flags (shifted coalesced loads; no LDS) ----
  const int* trow = tgt + b * HW_ + i0 * W_;
  int t0 = trow[j], t1 = trow[W_ + j];
  int t2 = hd1 ? trow[2 * W_ + j] : 0;
  int t0r = (j < W_ - 1) ? trow[j + 1] : t0;
  int t1r = (j < W_ - 1) ? trow[W_ + j + 1] : t1;
  bool bnd0 = (t0 == IGN_) || (t1 != t0) || (t0r != t0);
  bool bnd1 = (t1 == IGN_) || (hd1 && t2 != t1) || (t1r != t1);

  // ---- dual row-DT min scans: wave shuffle scan + cross-wave combine ----
  int s0 = bnd0 ? 0 : BIGI_, s1 = bnd1 ? 0 : BIGI_;
  int a0 = s0 - j, c0 = s0 + j, a1 = s1 - j, c1 = s1 + j;
  #pragma unroll
  for (int o = 1; o < 64; o <<= 1) {
    int v0 = __shfl_up(a0, o), v1 = __shfl_up(a1, o);
    if (lane >= o) { a0 = min(a0, v0); a1 = min(a1, v1); }
    int w0 = __shfl_down(c0, o), w1 = __shfl_down(c1, o);
    if (lane + o < 64) { c0 = min(c0, w0); c1 = min(c1, w1); }
  }
  if (lane == 63) { wtot[0][wv] = a0; wtot[2][wv] = a1; }
  if (lane == 0)  { wtot[1][wv] = c0; wtot[3][wv] = c1; }
  __syncthreads();
  #pragma unroll
  for (int w = 0; w < 5; ++w) {
    if (w < wv) { a0 = min(a0, wtot[0][w]); a1 = min(a1, wtot[2][w]); }
    if (w > wv) { c0 = min(c0, wtot[1][w]); c1 = min(c1, wtot[3][w]); }
  }
  R[(b * H_ + i0) * W_ + j] = min(a0 + j, c0 - j);
  R[(b * H_ + i1) * W_ + j] = min(a1 + j, c1 - j);

  // ---- fused softmax/KL channel loop (scalar accumulators only) ----
  const float* baseA = sl + (size_t)b * CHW_ + i0 * W_ + j;
  float seA = 0.f, EA = 0.f, dAB = 0.f, drA = 0.f, seAr = 0.f, xtA = 0.f;
  float seB = 0.f, EB = 0.f, dB2 = 0.f, drB = 0.f, seBr = 0.f, xtB = 0.f;
  float se2 = 0.f;
  bool hr = (j < W_ - 1);
  #pragma unroll
  for (int c = 0; c < C_; ++c) {
    float xA = baseA[c * HW_];
    float xB = baseA[c * HW_ + W_];
    float x2 = hd1 ? baseA[c * HW_ + 2 * W_] : 0.f;
    float xrA = hr ? baseA[c * HW_ + 1] : xA;        // right neighbor, L1-hit
    float xrB = hr ? baseA[c * HW_ + W_ + 1] : xB;
    float eAc = __expf(xA), eBc = __expf(xB);
    seA += eAc; EA += eAc * xA; dAB += eAc * xB; drA += eAc * xrA;
    seB += eBc; EB += eBc * xB; dB2 += eBc * x2; drB += eBc * xrB;
    se2 += __expf(x2);
    seAr += __expf(xrA); seBr += __expf(xrB);
    if (c == t0) xtA = xA;
    if (c == t1) xtB = xB;
  }
  float lzA = __logf(seA), lzB = __logf(seB);
  float SvA = EA / seA - lzA, SvB = EB / seB - lzB;
  float nll = ((t0 != IGN_) ? (lzA - xtA) : 0.f) + ((t1 != IGN_) ? (lzB - xtB) : 0.f);
  // down-KL: row i1 is row i0's down neighbor; row i0+2 is row i1's
  float klA = SvA - dAB / seA + lzB;
  float klB = hd1 ? (SvB - dB2 / seB + __logf(se2)) : 0.f;
  // right-KL: neighbor logZ recomputed (bitwise identical to neighbor's own)
  float lzrA = __logf(seAr), lzrB = __logf(seBr);
  if (hr) {
    klA += SvA - drA / seA + lzrA;
    klB += SvB - drB / seB + lzrB;
  }
  int gidx = (b * H_ + i0) * W_ + j;
  logZ[gidx] = lzA; S[gidx] = SvA; kl_map[gidx] = klA;
  logZ[gidx + W_] = lzB; S[gidx + W_] = SvB; kl_map[gidx + W_] = klB;
  atomicAdd(&sh[eps_bin(klA, et)], 1);
  atomicAdd(&sh[eps_bin(klB, et)], 1);
  __syncthreads();
  for (int e2 = j; e2 < 257; e2 += 320)
    if (sh[e2]) atomicAdd(&hist[e2], sh[e2]);
  block_reduce_add_w(nll, out, 5);
}

// ---------------- K2: column combine + (block 0) eps selection --------------
__global__ __launch_bounds__(H_) void k_coldt(const int* __restrict__ R, int* __restrict__ dist,
                                              const int* __restrict__ hist, float* __restrict__ eps_sel) {
  int b = blockIdx.x / W_, j = blockIdx.x % W_, tid = threadIdx.x;
  __shared__ int lev[9][H_];
  lev[0][tid] = R[(b * H_ + tid) * W_ + j];
  int Ri = lev[0][tid];
  for (int l = 1; l <= 8; ++l) {
    int half = 1 << (l - 1);
    __syncthreads();
    int other = (tid + half < H_) ? lev[l - 1][tid + half] : INF_;
    lev[l][tid] = min(lev[l - 1][tid], other);
  }
  __syncthreads();
  int i0 = tid;
  auto feas = [&](int dd) -> bool {
    int lo = max(0, i0 - dd), hi = min(H_ - 1, i0 + dd);
    int len = hi - lo + 1;
    int l = 31 - __clz(len);
    int m = min(lev[l][lo], lev[l][hi - (1 << l) + 1]);
    return m <= dd;
  };
  int d;
  int hi = min(Ri, 512);                 // d <= R[i0]
  if (!feas(hi)) d = B_ + 1 + H_ + W_;   // no seed in image
  else {
    int lo = 0;
    while (lo < hi) { int mid = (lo + hi) >> 1; if (feas(mid)) hi = mid; else lo = mid + 1; }
    d = lo;
  }
  dist[(b * H_ + i0) * W_ + j] = d;
  // block 0: eps via suffix scan of hist (bins 1..256)
  if (blockIdx.x == 0) {
    __shared__ int g[256];
    __shared__ int bestk;
    if (tid < 256) g[tid] = hist[tid + 1];
    if (tid == 0) bestk = NEPS_ - 1;
    __syncthreads();
    #pragma unroll
    for (int ofs = 1; ofs < 256; ofs <<= 1) {
      int v = 0;
      if (tid < 256) v = g[tid] + ((tid + ofs < 256) ? g[tid + ofs] : 0);
      __syncthreads();
      if (tid < 256) g[tid] = v;
      __syncthreads();
    }
    if (tid < 256 && g[tid] <= 5120) atomicMin(&bestk, tid);
    __syncthreads();
    if (tid == 0) eps_sel[0] = EPS.v[bestk];
  }
}

// ---------------- K3: mask+direction+dterm + in-block sparse CE -------------
__global__ __launch_bounds__(256) void k_maskce(const float* __restrict__ sl, const float* __restrict__ logZ,
                                                const float* __restrict__ S, const float* __restrict__ kl_map,
                                                const int* __restrict__ dist, const float* __restrict__ eps_sel,
                                                float* __restrict__ out) {
  const int nx9[9] = {1,-1,0,0,-1,1,-1,1,0};
  const int ny9[9] = {0,0,-1,1,1,1,-1,-1,0};
  int tid = threadIdx.x;
  int b = blockIdx.z;
  int i0 = blockIdx.y * 16, j0 = blockIdx.x * 16;
  float eps = eps_sel[0];
  __shared__ float kt[18][19];
  __shared__ int   dt_[18][19];
  for (int e = tid; e < 324; e += 256) {
    int r = e / 18, cc = e - r * 18;
    int gi = i0 - 1 + r, gj = j0 - 1 + cc;
    bool in = (gi >= 0 && gi < H_ && gj >= 0 && gj < W_);
    int gidx = (b * H_ + gi) * W_ + gj;
    kt[r][cc]  = in ? kl_map[gidx] : -1e30f;
    dt_[r][cc] = in ? dist[gidx] : 100000;
  }
  __syncthreads();
  int li = tid >> 4, lj = tid & 15;
  bool mask = false;
  #pragma unroll
  for (int dr = 0; dr < 3; ++dr)
    #pragma unroll
    for (int dc = 0; dc < 3; ++dc)
      mask |= (kt[li + dr][lj + dc] > eps);
  int best = INF_, dir = 0;
  #pragma unroll
  for (int k = 0; k < 9; ++k) {
    int r = dt_[li + 1 + nx9[k]][lj + 1 + ny9[k]];
    if (r < best) { best = r; dir = k; }
  }
  bool valid = mask && (dir != 8);
  float acc = valid ? fminf((float)dt_[li + 1][lj + 1], 20.f) * (1.f / 20.f) : 0.f;
  // compact valid pixels into LDS list
  __shared__ int list_[256];
  __shared__ int woff[4];
  __shared__ int tot_s;
  int lane = tid & 63, wid = tid >> 6;
  unsigned long long vote = __ballot(valid);
  if (lane == 0) woff[wid] = __popcll(vote);
  __syncthreads();
  if (tid == 0) {
    int c0 = woff[0], c1 = woff[1], c2 = woff[2], c3 = woff[3];
    tot_s = c0 + c1 + c2 + c3;
    woff[0] = 0; woff[1] = c0; woff[2] = c0 + c1; woff[3] = c0 + c1 + c2;
  }
  __syncthreads();
  if (valid)
    list_[woff[wid] + __popcll(vote & ((1ULL << lane) - 1ULL))] = tid | (min(dir, 7) << 8);
  __syncthreads();
  int cnt = tot_s;
  const float* bse = sl + (size_t)b * CHW_;
  // CE: 8 lanes per entry (lane k = neighbor k)
  for (int base0 = 0; base0 < cnt; base0 += 32) {
    int e = base0 + (tid >> 3), k = tid & 7;
    float ce = 0.f;
    if (e < cnt) {
      int w = list_[e];
      int label = w >> 8, lpos = w & 255;
      int i = i0 + (lpos >> 4), j = j0 + (lpos & 15);
      int pix = i * W_ + j;
      float lzc = logZ[b * HW_ + pix];
      int ic = min(max(i + nx9[k], 0), H_ - 1);
      int jc = min(max(j + ny9[k], 0), W_ - 1);
      int npx = ic * W_ + jc;
      float lzn = logZ[b * HW_ + npx], Sn = S[b * HW_ + npx];
      float dot = 0.f;
      #pragma unroll
      for (int c = 0; c < C_; ++c)
        dot += __expf(bse[c * HW_ + npx] - lzn) * bse[c * HW_ + pix];
      float kv = Sn - dot + lzc;
      float kmax = kv;
      #pragma unroll
      for (int o = 1; o < 8; o <<= 1) kmax = fmaxf(kmax, __shfl_xor(kmax, o));
      float ssum = __expf(kv - kmax);
      #pragma unroll
      for (int o = 1; o < 8; o <<= 1) ssum += __shfl_xor(ssum, o);
      float kll = __shfl(kv, (lane & ~7) | label);
      if (k == 0) ce = kmax + __logf(ssum) - kll;
    }
    acc += ce;
  }
  block_reduce_add_w(acc, out, 4);
}

// ---------------- launch -----------------------------------------------------
extern "C" void kernel_launch(void* const* d_in, const int* in_sizes, int n_in,
                              void* d_out, int out_size, void* d_ws, size_t ws_size,
                              hipStream_t stream) {
  const float* sl  = (const float*)d_in[0];
  const int*   tgt = (const int*)d_in[1];
  float* out = (float*)d_out;

  int*   hist    = (int*)d_ws;                 // 257 ints
  float* eps_sel = (float*)d_ws + 320;         // inside zeroed 2 KB region
  float* logZ    = (float*)d_ws + 512;
  float* S       = logZ + NPIX_;
  float* kl_map  = S + NPIX_;
  int*   dist    = (int*)(kl_map + NPIX_);
  int*   R       = dist + NPIX_;

  hipMemsetAsync(d_ws, 0, 2048, stream);
  hipMemsetAsync(d_out, 0, sizeof(float), stream);
  k_front<<<B_ * (H_ / 2), W_, 0, stream>>>(sl, tgt, R, logZ, S, kl_map, hist, out);
  k_coldt<<<B_ * W_, H_, 0, stream>>>(R, dist, hist, eps_sel);
  k_maskce<<<dim3(W_ / 16, H_ / 16, B_), 256, 0, stream>>>(sl, logZ, S, kl_map, dist, eps_sel, out);
}

// Round 2
// 149.597 us; speedup vs baseline: 1.0348x; 1.0348x over previous
//
#include <hip/hip_runtime.h>
#include <math.h>

#define B_    4
#define C_    19
#define H_    320
#define W_    320
#define HW_   (H_*W_)
#define CHW_  (C_*HW_)
#define NPIX_ (B_*HW_)
#define NEPS_ 256
#define BIGI_ (1<<20)
#define INF_  0x3fffffff
#define IGN_  255

// Compile-time exact replica of the reference eps chain: e0=1e-5f, e_{k+1}=e_k*1.2f
struct EpsTab { float v[NEPS_]; };
static constexpr EpsTab make_eps() {
  EpsTab t{}; float e = 1e-5f;
  for (int k = 0; k < NEPS_; ++k) { t.v[k] = e; e = e * 1.2f; }
  return t;
}
__device__ __constant__ EpsTab EPS = make_eps();

// ---------------- reduction helper (nw full waves) ---------------------------
__device__ __forceinline__ void block_reduce_add_w(float v, float* out, int nw) {
  #pragma unroll
  for (int o = 32; o > 0; o >>= 1) v += __shfl_down(v, o);
  __shared__ float shr[8];
  int lane = threadIdx.x & 63, wid = threadIdx.x >> 6;
  if (lane == 0) shr[wid] = v;
  __syncthreads();
  if (threadIdx.x == 0) {
    float s = 0.f;
    for (int w = 0; w < nw; ++w) s += shr[w];
    atomicAdd(out, s);
  }
}

__device__ __forceinline__ int eps_bin(float kl, const float* et) {
  // #{k : e_k < kl}, log2 guess + exact correction (identical compares to ref)
  if (!(kl > 1e-5f)) return 0;
  int g = (int)((__log2f(kl) + 16.6096404f) * 3.8017840f);
  g = min(max(g, 0), NEPS_ - 1);
  while (g < NEPS_ && et[g] < kl) ++g;
  while (g > 0 && !(et[g - 1] < kl)) --g;
  return g;
}

// ---------------- K0: flat per-pixel softmax/KL/nll/hist --------------------
// One thread per pixel, linear index -> perfectly coalesced loads (pixel p and
// p+1 are contiguous in memory; +W_ down-neighbor and +1 right-neighbor loads
// are contiguous streams too). Down/right neighbor softmax stats recomputed
// bitwise-identically (same __expf accumulation order as the neighbor's own).
// 1600 blocks x 256 threads = 25 waves/CU: latency-hiding via occupancy + 38
// hoisted loads/thread. No scans, no cross-thread deps, 2 barriers total.
__global__ __launch_bounds__(256) void k_soft(const float* __restrict__ sl, const int* __restrict__ tgt,
                                              float* __restrict__ logZ, float* __restrict__ S,
                                              float* __restrict__ kl_map, int* __restrict__ hist,
                                              float* __restrict__ out) {
  int tid = blockIdx.x * 256 + threadIdx.x;      // 0..NPIX_-1, exact cover
  int b = tid / HW_, p = tid - b * HW_;
  int i = p / W_, j = p - i * W_;
  bool hd = (i < H_ - 1), hr = (j < W_ - 1);
  __shared__ float et[NEPS_];
  __shared__ int sh[257];
  et[threadIdx.x] = EPS.v[threadIdx.x];
  sh[threadIdx.x] = 0;
  if (threadIdx.x == 0) sh[256] = 0;

  const float* base = sl + (size_t)b * CHW_ + p;
  float xA[C_], xB[C_];
  #pragma unroll
  for (int c = 0; c < C_; ++c) xA[c] = base[c * HW_];
  #pragma unroll
  for (int c = 0; c < C_; ++c) xB[c] = hd ? base[c * HW_ + W_] : 0.f;
  int t0 = tgt[b * HW_ + p];

  float seA = 0.f, EA = 0.f, dAB = 0.f, drA = 0.f, seB = 0.f, seAr = 0.f, xtA = 0.f;
  #pragma unroll
  for (int c = 0; c < C_; ++c) {
    float xr = hr ? base[c * HW_ + 1] : xA[c];   // right neighbor, L1/L2-hit
    float eAc = __expf(xA[c]);
    seA += eAc; EA += eAc * xA[c];
    dAB += eAc * xB[c];
    drA += eAc * xr;
    seB += __expf(xB[c]);                        // matches down-pixel's own seA order
    seAr += __expf(xr);                          // matches right-pixel's own seA order
    if (c == t0) xtA = xA[c];
  }
  float lzA = __logf(seA);
  float SvA = EA / seA - lzA;
  float nll = (t0 != IGN_) ? (lzA - xtA) : 0.f;
  float kl = hd ? (SvA - dAB / seA + __logf(seB)) : 0.f;   // kl_tb (pad 0 at last row)
  if (hr) kl += SvA - drA / seA + __logf(seAr);            // + kl_lr (pad 0 at last col)
  logZ[tid] = lzA; S[tid] = SvA; kl_map[tid] = kl;
  __syncthreads();                       // et/sh init visible
  atomicAdd(&sh[eps_bin(kl, et)], 1);
  __syncthreads();
  if (sh[threadIdx.x]) atomicAdd(&hist[threadIdx.x], sh[threadIdx.x]);
  if (threadIdx.x == 0 && sh[256]) atomicAdd(&hist[256], sh[256]);
  block_reduce_add_w(nll, out, 4);
}

// ---------------- K1: row distance transform (targets only) -----------------
__global__ __launch_bounds__(320) void k_rowdt(const int* __restrict__ tgt, int* __restrict__ R) {
  int bid = blockIdx.x;                  // b*H_ + i
  int b = bid / H_, i = bid - b * H_;
  int j = threadIdx.x, lane = j & 63, wv = j >> 6;
  bool hd = (i < H_ - 1);
  const int* trow = tgt + b * HW_ + i * W_;
  int t0 = trow[j];
  int t1 = hd ? trow[W_ + j] : t0;
  int t0r = (j < W_ - 1) ? trow[j + 1] : t0;
  bool bnd = (t0 == IGN_) || (t1 != t0) || (t0r != t0);
  int s = bnd ? 0 : BIGI_;
  int a = s - j, c = s + j;
  #pragma unroll
  for (int o = 1; o < 64; o <<= 1) {
    int v = __shfl_up(a, o);
    if (lane >= o) a = min(a, v);
    int w = __shfl_down(c, o);
    if (lane + o < 64) c = min(c, w);
  }
  __shared__ int wa[5], wc[5];
  if (lane == 63) wa[wv] = a;
  if (lane == 0)  wc[wv] = c;
  __syncthreads();
  #pragma unroll
  for (int w = 0; w < 5; ++w) {
    if (w < wv) a = min(a, wa[w]);
    if (w > wv) c = min(c, wc[w]);
  }
  R[bid * W_ + j] = min(a + j, c - j);
}

// ---------------- K2: column combine + (block 0) eps selection --------------
__global__ __launch_bounds__(H_) void k_coldt(const int* __restrict__ R, int* __restrict__ dist,
                                              const int* __restrict__ hist, float* __restrict__ eps_sel) {
  int b = blockIdx.x / W_, j = blockIdx.x % W_, tid = threadIdx.x;
  __shared__ int lev[9][H_];
  lev[0][tid] = R[(b * H_ + tid) * W_ + j];
  int Ri = lev[0][tid];
  for (int l = 1; l <= 8; ++l) {
    int half = 1 << (l - 1);
    __syncthreads();
    int other = (tid + half < H_) ? lev[l - 1][tid + half] : INF_;
    lev[l][tid] = min(lev[l - 1][tid], other);
  }
  __syncthreads();
  int i0 = tid;
  auto feas = [&](int dd) -> bool {
    int lo = max(0, i0 - dd), hi = min(H_ - 1, i0 + dd);
    int len = hi - lo + 1;
    int l = 31 - __clz(len);
    int m = min(lev[l][lo], lev[l][hi - (1 << l) + 1]);
    return m <= dd;
  };
  int d;
  int hi = min(Ri, 512);                 // d <= R[i0]
  if (!feas(hi)) d = B_ + 1 + H_ + W_;   // no seed in image
  else {
    int lo = 0;
    while (lo < hi) { int mid = (lo + hi) >> 1; if (feas(mid)) hi = mid; else lo = mid + 1; }
    d = lo;
  }
  dist[(b * H_ + i0) * W_ + j] = d;
  // block 0: eps via suffix scan of hist (bins 1..256)
  if (blockIdx.x == 0) {
    __shared__ int g[256];
    __shared__ int bestk;
    if (tid < 256) g[tid] = hist[tid + 1];
    if (tid == 0) bestk = NEPS_ - 1;
    __syncthreads();
    #pragma unroll
    for (int ofs = 1; ofs < 256; ofs <<= 1) {
      int v = 0;
      if (tid < 256) v = g[tid] + ((tid + ofs < 256) ? g[tid + ofs] : 0);
      __syncthreads();
      if (tid < 256) g[tid] = v;
      __syncthreads();
    }
    if (tid < 256 && g[tid] <= 5120) atomicMin(&bestk, tid);
    __syncthreads();
    if (tid == 0) eps_sel[0] = EPS.v[bestk];
  }
}

// ---------------- K3: mask+direction+dterm + in-block sparse CE -------------
__global__ __launch_bounds__(256) void k_maskce(const float* __restrict__ sl, const float* __restrict__ logZ,
                                                const float* __restrict__ S, const float* __restrict__ kl_map,
                                                const int* __restrict__ dist, const float* __restrict__ eps_sel,
                                                float* __restrict__ out) {
  const int nx9[9] = {1,-1,0,0,-1,1,-1,1,0};
  const int ny9[9] = {0,0,-1,1,1,1,-1,-1,0};
  int tid = threadIdx.x;
  int b = blockIdx.z;
  int i0 = blockIdx.y * 16, j0 = blockIdx.x * 16;
  float eps = eps_sel[0];
  __shared__ float kt[18][19];
  __shared__ int   dt_[18][19];
  for (int e = tid; e < 324; e += 256) {
    int r = e / 18, cc = e - r * 18;
    int gi = i0 - 1 + r, gj = j0 - 1 + cc;
    bool in = (gi >= 0 && gi < H_ && gj >= 0 && gj < W_);
    int gidx = (b * H_ + gi) * W_ + gj;
    kt[r][cc]  = in ? kl_map[gidx] : -1e30f;
    dt_[r][cc] = in ? dist[gidx] : 100000;
  }
  __syncthreads();
  int li = tid >> 4, lj = tid & 15;
  bool mask = false;
  #pragma unroll
  for (int dr = 0; dr < 3; ++dr)
    #pragma unroll
    for (int dc = 0; dc < 3; ++dc)
      mask |= (kt[li + dr][lj + dc] > eps);
  int best = INF_, dir = 0;
  #pragma unroll
  for (int k = 0; k < 9; ++k) {
    int r = dt_[li + 1 + nx9[k]][lj + 1 + ny9[k]];
    if (r < best) { best = r; dir = k; }
  }
  bool valid = mask && (dir != 8);
  float acc = valid ? fminf((float)dt_[li + 1][lj + 1], 20.f) * (1.f / 20.f) : 0.f;
  // compact valid pixels into LDS list
  __shared__ int list_[256];
  __shared__ int woff[4];
  __shared__ int tot_s;
  int lane = tid & 63, wid = tid >> 6;
  unsigned long long vote = __ballot(valid);
  if (lane == 0) woff[wid] = __popcll(vote);
  __syncthreads();
  if (tid == 0) {
    int c0 = woff[0], c1 = woff[1], c2 = woff[2], c3 = woff[3];
    tot_s = c0 + c1 + c2 + c3;
    woff[0] = 0; woff[1] = c0; woff[2] = c0 + c1; woff[3] = c0 + c1 + c2;
  }
  __syncthreads();
  if (valid)
    list_[woff[wid] + __popcll(vote & ((1ULL << lane) - 1ULL))] = tid | (min(dir, 7) << 8);
  __syncthreads();
  int cnt = tot_s;
  const float* bse = sl + (size_t)b * CHW_;
  // CE: 8 lanes per entry (lane k = neighbor k)
  for (int base0 = 0; base0 < cnt; base0 += 32) {
    int e = base0 + (tid >> 3), k = tid & 7;
    float ce = 0.f;
    if (e < cnt) {
      int w = list_[e];
      int label = w >> 8, lpos = w & 255;
      int i = i0 + (lpos >> 4), j = j0 + (lpos & 15);
      int pix = i * W_ + j;
      float lzc = logZ[b * HW_ + pix];
      int ic = min(max(i + nx9[k], 0), H_ - 1);
      int jc = min(max(j + ny9[k], 0), W_ - 1);
      int npx = ic * W_ + jc;
      float lzn = logZ[b * HW_ + npx], Sn = S[b * HW_ + npx];
      float dot = 0.f;
      #pragma unroll
      for (int c = 0; c < C_; ++c)
        dot += __expf(bse[c * HW_ + npx] - lzn) * bse[c * HW_ + pix];
      float kv = Sn - dot + lzc;
      float kmax = kv;
      #pragma unroll
      for (int o = 1; o < 8; o <<= 1) kmax = fmaxf(kmax, __shfl_xor(kmax, o));
      float ssum = __expf(kv - kmax);
      #pragma unroll
      for (int o = 1; o < 8; o <<= 1) ssum += __shfl_xor(ssum, o);
      float kll = __shfl(kv, (lane & ~7) | label);
      if (k == 0) ce = kmax + __logf(ssum) - kll;
    }
    acc += ce;
  }
  block_reduce_add_w(acc, out, 4);
}

// ---------------- launch -----------------------------------------------------
extern "C" void kernel_launch(void* const* d_in, const int* in_sizes, int n_in,
                              void* d_out, int out_size, void* d_ws, size_t ws_size,
                              hipStream_t stream) {
  const float* sl  = (const float*)d_in[0];
  const int*   tgt = (const int*)d_in[1];
  float* out = (float*)d_out;

  int*   hist    = (int*)d_ws;                 // 257 ints
  float* eps_sel = (float*)d_ws + 320;         // inside zeroed 2 KB region
  float* logZ    = (float*)d_ws + 512;
  float* S       = logZ + NPIX_;
  float* kl_map  = S + NPIX_;
  int*   dist    = (int*)(kl_map + NPIX_);
  int*   R       = dist + NPIX_;

  hipMemsetAsync(d_ws, 0, 2048, stream);
  hipMemsetAsync(d_out, 0, sizeof(float), stream);
  k_rowdt<<<B_ * H_, W_, 0, stream>>>(tgt, R);
  k_soft<<<NPIX_ / 256, 256, 0, stream>>>(sl, tgt, logZ, S, kl_map, hist, out);
  k_coldt<<<B_ * W_, H_, 0, stream>>>(R, dist, hist, eps_sel);
  k_maskce<<<dim3(W_ / 16, H_ / 16, B_), 256, 0, stream>>>(sl, logZ, S, kl_map, dist, eps_sel, out);
}

// Round 3
// 141.050 us; speedup vs baseline: 1.0975x; 1.0606x over previous
//
#include <hip/hip_runtime.h>
#include <math.h>

#define B_    4
#define C_    19
#define H_    320
#define W_    320
#define HW_   (H_*W_)
#define CHW_  (C_*HW_)
#define NPIX_ (B_*HW_)
#define NEPS_ 256
#define BIGI_ (1<<20)
#define INF_  0x3fffffff
#define IGN_  255

// Compile-time exact replica of the reference eps chain: e0=1e-5f, e_{k+1}=e_k*1.2f
struct EpsTab { float v[NEPS_]; };
static constexpr EpsTab make_eps() {
  EpsTab t{}; float e = 1e-5f;
  for (int k = 0; k < NEPS_; ++k) { t.v[k] = e; e = e * 1.2f; }
  return t;
}
__device__ __constant__ EpsTab EPS = make_eps();

// ---------------- reduction helper (nw full waves) ---------------------------
__device__ __forceinline__ void block_reduce_add_w(float v, float* out, int nw) {
  #pragma unroll
  for (int o = 32; o > 0; o >>= 1) v += __shfl_down(v, o);
  __shared__ float shr[8];
  int lane = threadIdx.x & 63, wid = threadIdx.x >> 6;
  if (lane == 0) shr[wid] = v;
  __syncthreads();
  if (threadIdx.x == 0) {
    float s = 0.f;
    for (int w = 0; w < nw; ++w) s += shr[w];
    atomicAdd(out, s);
  }
}

__device__ __forceinline__ int eps_bin(float kl, const float* et) {
  // #{k : e_k < kl}, log2 guess + exact correction (identical compares to ref)
  if (!(kl > 1e-5f)) return 0;
  int g = (int)((__log2f(kl) + 16.6096404f) * 3.8017840f);
  g = min(max(g, 0), NEPS_ - 1);
  while (g < NEPS_ && et[g] < kl) ++g;
  while (g > 0 && !(et[g - 1] < kl)) --g;
  return g;
}

// ---------------- K0: per-QUAD softmax/KL/nll/hist (float4 vectorized) ------
// 4 consecutive pixels per thread. Per channel: one float4 own-load, one
// float4 down-load, one scalar right-edge load (3 load instrs for 4 pixels vs
// 12 scalar). Right-neighbor softmax stats for pixels 0..2 come from the OWN
// float4 lanes / neighbor-pixel accumulators -- bitwise identical to the
// neighbor's own accumulation (same __expf order), proven absmax=0.0 in
// rounds 1-2. Only pixel 3 reads pc[4] (L1-hit: next thread's own line).
// No register arrays: everything consumed per-channel into ~30 scalar accums.
__global__ __launch_bounds__(256) void k_soft(const float* __restrict__ sl, const int* __restrict__ tgt,
                                              float* __restrict__ logZ, float* __restrict__ S,
                                              float* __restrict__ kl_map, int* __restrict__ hist,
                                              float* __restrict__ out) {
  int t = blockIdx.x * 256 + threadIdx.x;        // quad index, 0..NPIX_/4-1
  int b = t / (HW_ / 4), q = t - b * (HW_ / 4);
  int p = q * 4;                                 // pixel base within image (j%4==0)
  int i = p / W_, j = p - i * W_;
  bool hd = (i < H_ - 1);
  bool hr3 = (j + 4 < W_);                       // pixel3 has a right neighbor
  __shared__ float et[NEPS_];
  __shared__ int sh[257];
  et[threadIdx.x] = EPS.v[threadIdx.x];
  sh[threadIdx.x] = 0;
  if (threadIdx.x == 0) sh[256] = 0;

  const float* base = sl + (size_t)b * CHW_ + p;
  int4 t4 = *(const int4*)(tgt + b * HW_ + p);

  float se0=0.f,se1=0.f,se2=0.f,se3=0.f, E0=0.f,E1=0.f,E2=0.f,E3=0.f;
  float dD0=0.f,dD1=0.f,dD2=0.f,dD3=0.f;   // sum eA*x_down
  float sB0=0.f,sB1=0.f,sB2=0.f,sB3=0.f;   // sum exp(x_down)
  float dR0=0.f,dR1=0.f,dR2=0.f,dR3=0.f;   // sum eA*x_right
  float sR3=0.f;                            // right-edge exp sum (pixel3)
  float xt0=0.f,xt1=0.f,xt2=0.f,xt3=0.f;
  #pragma unroll
  for (int c = 0; c < C_; ++c) {
    const float* pc = base + c * HW_;
    float4 xo = *(const float4*)pc;
    float4 xd = hd ? *(const float4*)(pc + W_) : make_float4(0.f,0.f,0.f,0.f);
    float xr = hr3 ? pc[4] : 0.f;
    float e0=__expf(xo.x), e1=__expf(xo.y), e2=__expf(xo.z), e3=__expf(xo.w);
    se0+=e0; E0+=e0*xo.x; se1+=e1; E1+=e1*xo.y;
    se2+=e2; E2+=e2*xo.z; se3+=e3; E3+=e3*xo.w;
    dD0+=e0*xd.x; dD1+=e1*xd.y; dD2+=e2*xd.z; dD3+=e3*xd.w;
    sB0+=__expf(xd.x); sB1+=__expf(xd.y); sB2+=__expf(xd.z); sB3+=__expf(xd.w);
    dR0+=e0*xo.y; dR1+=e1*xo.z; dR2+=e2*xo.w; dR3+=e3*xr;
    sR3+=__expf(xr);
    if (c == t4.x) xt0 = xo.x;
    if (c == t4.y) xt1 = xo.y;
    if (c == t4.z) xt2 = xo.z;
    if (c == t4.w) xt3 = xo.w;
  }
  float lz0=__logf(se0), lz1=__logf(se1), lz2=__logf(se2), lz3=__logf(se3);
  float Sv0=E0/se0-lz0, Sv1=E1/se1-lz1, Sv2=E2/se2-lz2, Sv3=E3/se3-lz3;
  float nll = ((t4.x!=IGN_)?(lz0-xt0):0.f) + ((t4.y!=IGN_)?(lz1-xt1):0.f)
            + ((t4.z!=IGN_)?(lz2-xt2):0.f) + ((t4.w!=IGN_)?(lz3-xt3):0.f);
  // kl_tb (0 at last row)
  float kl0 = hd ? (Sv0 - dD0/se0 + __logf(sB0)) : 0.f;
  float kl1 = hd ? (Sv1 - dD1/se1 + __logf(sB1)) : 0.f;
  float kl2 = hd ? (Sv2 - dD2/se2 + __logf(sB2)) : 0.f;
  float kl3 = hd ? (Sv3 - dD3/se3 + __logf(sB3)) : 0.f;
  // kl_lr: pixels 0..2 always have right nbr (max col here is 318); use
  // neighbor-pixel accumulators (bitwise = neighbor's own softmax stats)
  kl0 += Sv0 - dR0/se0 + lz1;
  kl1 += Sv1 - dR1/se1 + lz2;
  kl2 += Sv2 - dR2/se2 + lz3;
  if (hr3) kl3 += Sv3 - dR3/se3 + __logf(sR3);
  int gp = b * HW_ + p;
  *(float4*)(logZ + gp)   = make_float4(lz0, lz1, lz2, lz3);
  *(float4*)(S + gp)      = make_float4(Sv0, Sv1, Sv2, Sv3);
  *(float4*)(kl_map + gp) = make_float4(kl0, kl1, kl2, kl3);
  __syncthreads();                       // et/sh init visible
  atomicAdd(&sh[eps_bin(kl0, et)], 1);
  atomicAdd(&sh[eps_bin(kl1, et)], 1);
  atomicAdd(&sh[eps_bin(kl2, et)], 1);
  atomicAdd(&sh[eps_bin(kl3, et)], 1);
  __syncthreads();
  if (sh[threadIdx.x]) atomicAdd(&hist[threadIdx.x], sh[threadIdx.x]);
  if (threadIdx.x == 0 && sh[256]) atomicAdd(&hist[256], sh[256]);
  block_reduce_add_w(nll, out, 4);
}

// ---------------- K1: row distance transform (targets only) -----------------
__global__ __launch_bounds__(320) void k_rowdt(const int* __restrict__ tgt, int* __restrict__ R) {
  int bid = blockIdx.x;                  // b*H_ + i
  int b = bid / H_, i = bid - b * H_;
  int j = threadIdx.x, lane = j & 63, wv = j >> 6;
  bool hd = (i < H_ - 1);
  const int* trow = tgt + b * HW_ + i * W_;
  int t0 = trow[j];
  int t1 = hd ? trow[W_ + j] : t0;
  int t0r = (j < W_ - 1) ? trow[j + 1] : t0;
  bool bnd = (t0 == IGN_) || (t1 != t0) || (t0r != t0);
  int s = bnd ? 0 : BIGI_;
  int a = s - j, c = s + j;
  #pragma unroll
  for (int o = 1; o < 64; o <<= 1) {
    int v = __shfl_up(a, o);
    if (lane >= o) a = min(a, v);
    int w = __shfl_down(c, o);
    if (lane + o < 64) c = min(c, w);
  }
  __shared__ int wa[5], wc[5];
  if (lane == 63) wa[wv] = a;
  if (lane == 0)  wc[wv] = c;
  __syncthreads();
  #pragma unroll
  for (int w = 0; w < 5; ++w) {
    if (w < wv) a = min(a, wa[w]);
    if (w > wv) c = min(c, wc[w]);
  }
  R[bid * W_ + j] = min(a + j, c - j);
}

// ---------------- K2: column combine + (block 0) eps selection --------------
__global__ __launch_bounds__(H_) void k_coldt(const int* __restrict__ R, int* __restrict__ dist,
                                              const int* __restrict__ hist, float* __restrict__ eps_sel) {
  int b = blockIdx.x / W_, j = blockIdx.x % W_, tid = threadIdx.x;
  __shared__ int lev[9][H_];
  lev[0][tid] = R[(b * H_ + tid) * W_ + j];
  int Ri = lev[0][tid];
  for (int l = 1; l <= 8; ++l) {
    int half = 1 << (l - 1);
    __syncthreads();
    int other = (tid + half < H_) ? lev[l - 1][tid + half] : INF_;
    lev[l][tid] = min(lev[l - 1][tid], other);
  }
  __syncthreads();
  int i0 = tid;
  auto feas = [&](int dd) -> bool {
    int lo = max(0, i0 - dd), hi = min(H_ - 1, i0 + dd);
    int len = hi - lo + 1;
    int l = 31 - __clz(len);
    int m = min(lev[l][lo], lev[l][hi - (1 << l) + 1]);
    return m <= dd;
  };
  int d;
  int hi = min(Ri, 512);                 // d <= R[i0]
  if (!feas(hi)) d = B_ + 1 + H_ + W_;   // no seed in image
  else {
    int lo = 0;
    while (lo < hi) { int mid = (lo + hi) >> 1; if (feas(mid)) hi = mid; else lo = mid + 1; }
    d = lo;
  }
  dist[(b * H_ + i0) * W_ + j] = d;
  // block 0: eps via suffix scan of hist (bins 1..256)
  if (blockIdx.x == 0) {
    __shared__ int g[256];
    __shared__ int bestk;
    if (tid < 256) g[tid] = hist[tid + 1];
    if (tid == 0) bestk = NEPS_ - 1;
    __syncthreads();
    #pragma unroll
    for (int ofs = 1; ofs < 256; ofs <<= 1) {
      int v = 0;
      if (tid < 256) v = g[tid] + ((tid + ofs < 256) ? g[tid + ofs] : 0);
      __syncthreads();
      if (tid < 256) g[tid] = v;
      __syncthreads();
    }
    if (tid < 256 && g[tid] <= 5120) atomicMin(&bestk, tid);
    __syncthreads();
    if (tid == 0) eps_sel[0] = EPS.v[bestk];
  }
}

// ---------------- K3: mask+direction+dterm + in-block sparse CE -------------
__global__ __launch_bounds__(256) void k_maskce(const float* __restrict__ sl, const float* __restrict__ logZ,
                                                const float* __restrict__ S, const float* __restrict__ kl_map,
                                                const int* __restrict__ dist, const float* __restrict__ eps_sel,
                                                float* __restrict__ out) {
  const int nx9[9] = {1,-1,0,0,-1,1,-1,1,0};
  const int ny9[9] = {0,0,-1,1,1,1,-1,-1,0};
  int tid = threadIdx.x;
  int b = blockIdx.z;
  int i0 = blockIdx.y * 16, j0 = blockIdx.x * 16;
  float eps = eps_sel[0];
  __shared__ float kt[18][19];
  __shared__ int   dt_[18][19];
  for (int e = tid; e < 324; e += 256) {
    int r = e / 18, cc = e - r * 18;
    int gi = i0 - 1 + r, gj = j0 - 1 + cc;
    bool in = (gi >= 0 && gi < H_ && gj >= 0 && gj < W_);
    int gidx = (b * H_ + gi) * W_ + gj;
    kt[r][cc]  = in ? kl_map[gidx] : -1e30f;
    dt_[r][cc] = in ? dist[gidx] : 100000;
  }
  __syncthreads();
  int li = tid >> 4, lj = tid & 15;
  bool mask = false;
  #pragma unroll
  for (int dr = 0; dr < 3; ++dr)
    #pragma unroll
    for (int dc = 0; dc < 3; ++dc)
      mask |= (kt[li + dr][lj + dc] > eps);
  int best = INF_, dir = 0;
  #pragma unroll
  for (int k = 0; k < 9; ++k) {
    int r = dt_[li + 1 + nx9[k]][lj + 1 + ny9[k]];
    if (r < best) { best = r; dir = k; }
  }
  bool valid = mask && (dir != 8);
  float acc = valid ? fminf((float)dt_[li + 1][lj + 1], 20.f) * (1.f / 20.f) : 0.f;
  // compact valid pixels into LDS list
  __shared__ int list_[256];
  __shared__ int woff[4];
  __shared__ int tot_s;
  int lane = tid & 63, wid = tid >> 6;
  unsigned long long vote = __ballot(valid);
  if (lane == 0) woff[wid] = __popcll(vote);
  __syncthreads();
  if (tid == 0) {
    int c0 = woff[0], c1 = woff[1], c2 = woff[2], c3 = woff[3];
    tot_s = c0 + c1 + c2 + c3;
    woff[0] = 0; woff[1] = c0; woff[2] = c0 + c1; woff[3] = c0 + c1 + c2;
  }
  __syncthreads();
  if (valid)
    list_[woff[wid] + __popcll(vote & ((1ULL << lane) - 1ULL))] = tid | (min(dir, 7) << 8);
  __syncthreads();
  int cnt = tot_s;
  const float* bse = sl + (size_t)b * CHW_;
  // CE: 8 lanes per entry (lane k = neighbor k)
  for (int base0 = 0; base0 < cnt; base0 += 32) {
    int e = base0 + (tid >> 3), k = tid & 7;
    float ce = 0.f;
    if (e < cnt) {
      int w = list_[e];
      int label = w >> 8, lpos = w & 255;
      int i = i0 + (lpos >> 4), j = j0 + (lpos & 15);
      int pix = i * W_ + j;
      float lzc = logZ[b * HW_ + pix];
      int ic = min(max(i + nx9[k], 0), H_ - 1);
      int jc = min(max(j + ny9[k], 0), W_ - 1);
      int npx = ic * W_ + jc;
      float lzn = logZ[b * HW_ + npx], Sn = S[b * HW_ + npx];
      float dot = 0.f;
      #pragma unroll
      for (int c = 0; c < C_; ++c)
        dot += __expf(bse[c * HW_ + npx] - lzn) * bse[c * HW_ + pix];
      float kv = Sn - dot + lzc;
      float kmax = kv;
      #pragma unroll
      for (int o = 1; o < 8; o <<= 1) kmax = fmaxf(kmax, __shfl_xor(kmax, o));
      float ssum = __expf(kv - kmax);
      #pragma unroll
      for (int o = 1; o < 8; o <<= 1) ssum += __shfl_xor(ssum, o);
      float kll = __shfl(kv, (lane & ~7) | label);
      if (k == 0) ce = kmax + __logf(ssum) - kll;
    }
    acc += ce;
  }
  block_reduce_add_w(acc, out, 4);
}

// ---------------- launch -----------------------------------------------------
extern "C" void kernel_launch(void* const* d_in, const int* in_sizes, int n_in,
                              void* d_out, int out_size, void* d_ws, size_t ws_size,
                              hipStream_t stream) {
  const float* sl  = (const float*)d_in[0];
  const int*   tgt = (const int*)d_in[1];
  float* out = (float*)d_out;

  int*   hist    = (int*)d_ws;                 // 257 ints
  float* eps_sel = (float*)d_ws + 320;         // inside zeroed 2 KB region
  float* logZ    = (float*)d_ws + 512;
  float* S       = logZ + NPIX_;
  float* kl_map  = S + NPIX_;
  int*   dist    = (int*)(kl_map + NPIX_);
  int*   R       = dist + NPIX_;

  hipMemsetAsync(d_ws, 0, 2048, stream);
  hipMemsetAsync(d_out, 0, sizeof(float), stream);
  k_rowdt<<<B_ * H_, W_, 0, stream>>>(tgt, R);
  k_soft<<<NPIX_ / 4 / 256, 256, 0, stream>>>(sl, tgt, logZ, S, kl_map, hist, out);
  k_coldt<<<B_ * W_, H_, 0, stream>>>(R, dist, hist, eps_sel);
  k_maskce<<<dim3(W_ / 16, H_ / 16, B_), 256, 0, stream>>>(sl, logZ, S, kl_map, dist, eps_sel, out);
}

// Round 4
// 139.488 us; speedup vs baseline: 1.1098x; 1.0112x over previous
//
#include <hip/hip_runtime.h>
#include <math.h>

#define B_    4
#define C_    19
#define H_    320
#define W_    320
#define HW_   (H_*W_)
#define CHW_  (C_*HW_)
#define NPIX_ (B_*HW_)
#define NEPS_ 256
#define BIGI_ (1<<20)
#define INF_  0x3fffffff
#define IGN_  255

// Compile-time exact replica of the reference eps chain: e0=1e-5f, e_{k+1}=e_k*1.2f
struct EpsTab { float v[NEPS_]; };
static constexpr EpsTab make_eps() {
  EpsTab t{}; float e = 1e-5f;
  for (int k = 0; k < NEPS_; ++k) { t.v[k] = e; e = e * 1.2f; }
  return t;
}
__device__ __constant__ EpsTab EPS = make_eps();

// ---------------- reduction helper (nw full waves) ---------------------------
__device__ __forceinline__ void block_reduce_add_w(float v, float* out, int nw) {
  #pragma unroll
  for (int o = 32; o > 0; o >>= 1) v += __shfl_down(v, o);
  __shared__ float shr[8];
  int lane = threadIdx.x & 63, wid = threadIdx.x >> 6;
  if (lane == 0) shr[wid] = v;
  __syncthreads();
  if (threadIdx.x == 0) {
    float s = 0.f;
    for (int w = 0; w < nw; ++w) s += shr[w];
    atomicAdd(out, s);
  }
}

__device__ __forceinline__ int eps_bin(float kl, const float* et) {
  // #{k : e_k < kl}, log2 guess + exact correction (identical compares to ref)
  if (!(kl > 1e-5f)) return 0;
  int g = (int)((__log2f(kl) + 16.6096404f) * 3.8017840f);
  g = min(max(g, 0), NEPS_ - 1);
  while (g < NEPS_ && et[g] < kl) ++g;
  while (g > 0 && !(et[g - 1] < kl)) --g;
  return g;
}

// ---------------- K1: row distance transform + workspace init ---------------
// Writes R TRANSPOSED (R_t[b][j][i]) so k_coldt's column loads are coalesced.
// Block 0 also zeroes hist/out, replacing two hipMemsetAsync dispatches
// (stream order makes the zeroes visible to k_soft / k_coldt).
__global__ __launch_bounds__(320) void k_rowdt(const int* __restrict__ tgt, int* __restrict__ Rt,
                                               int* __restrict__ hist, float* __restrict__ out) {
  int bid = blockIdx.x;                  // b*H_ + i
  int b = bid / H_, i = bid - b * H_;
  int j = threadIdx.x, lane = j & 63, wv = j >> 6;
  if (bid == 0) {
    if (j < 257) hist[j] = 0;
    if (j == 319) out[0] = 0.f;
  }
  bool hd = (i < H_ - 1);
  const int* trow = tgt + b * HW_ + i * W_;
  int t0 = trow[j];
  int t1 = hd ? trow[W_ + j] : t0;
  int t0r = (j < W_ - 1) ? trow[j + 1] : t0;
  bool bnd = (t0 == IGN_) || (t1 != t0) || (t0r != t0);
  int s = bnd ? 0 : BIGI_;
  int a = s - j, c = s + j;
  #pragma unroll
  for (int o = 1; o < 64; o <<= 1) {
    int v = __shfl_up(a, o);
    if (lane >= o) a = min(a, v);
    int w = __shfl_down(c, o);
    if (lane + o < 64) c = min(c, w);
  }
  __shared__ int wa[5], wc[5];
  if (lane == 63) wa[wv] = a;
  if (lane == 0)  wc[wv] = c;
  __syncthreads();
  #pragma unroll
  for (int w = 0; w < 5; ++w) {
    if (w < wv) a = min(a, wa[w]);
    if (w > wv) c = min(c, wc[w]);
  }
  Rt[(b * W_ + j) * H_ + i] = min(a + j, c - j);   // transposed store
}

// ---------------- K0: per-PAIR softmax/KL/nll/hist (float2 vectorized) ------
// 2 consecutive pixels per thread: 800 blocks (3.1 waves/SIMD -- 2x the TLP of
// the float4 version) while keeping 3 load-instrs per channel. Right-neighbor
// stats for pixel0 come from pixel1's own accumulators (bitwise identical,
// proven absmax=0.0 rounds 1-3); pixel1's right needs one scalar load pc[2].
__global__ __launch_bounds__(256) void k_soft(const float* __restrict__ sl, const int* __restrict__ tgt,
                                              float* __restrict__ logZ, float* __restrict__ S,
                                              float* __restrict__ kl_map, int* __restrict__ hist,
                                              float* __restrict__ out) {
  int t = blockIdx.x * 256 + threadIdx.x;        // pair index, 0..NPIX_/2-1
  int b = t / (HW_ / 2), q = t - b * (HW_ / 2);
  int p = q * 2;                                 // pixel base (j even)
  int i = p / W_, j = p - i * W_;
  bool hd = (i < H_ - 1);
  bool hr1 = (j + 2 < W_);                       // pixel1 has a right neighbor
  __shared__ float et[NEPS_];
  __shared__ int sh[257];
  et[threadIdx.x] = EPS.v[threadIdx.x];
  sh[threadIdx.x] = 0;
  if (threadIdx.x == 0) sh[256] = 0;

  const float* base = sl + (size_t)b * CHW_ + p;
  int2 t2 = *(const int2*)(tgt + b * HW_ + p);

  float se0=0.f,se1=0.f, E0=0.f,E1=0.f;
  float dD0=0.f,dD1=0.f, sB0=0.f,sB1=0.f;
  float dR0=0.f,dR1=0.f, sR1=0.f;
  float xt0=0.f,xt1=0.f;
  #pragma unroll
  for (int c = 0; c < C_; ++c) {
    const float* pc = base + c * HW_;
    float2 xo = *(const float2*)pc;
    float2 xd = hd ? *(const float2*)(pc + W_) : make_float2(0.f, 0.f);
    float xr = hr1 ? pc[2] : 0.f;
    float e0 = __expf(xo.x), e1 = __expf(xo.y);
    se0 += e0; E0 += e0 * xo.x;
    se1 += e1; E1 += e1 * xo.y;
    dD0 += e0 * xd.x; dD1 += e1 * xd.y;
    sB0 += __expf(xd.x); sB1 += __expf(xd.y);
    dR0 += e0 * xo.y; dR1 += e1 * xr;
    sR1 += __expf(xr);
    if (c == t2.x) xt0 = xo.x;
    if (c == t2.y) xt1 = xo.y;
  }
  float lz0 = __logf(se0), lz1 = __logf(se1);
  float Sv0 = E0 / se0 - lz0, Sv1 = E1 / se1 - lz1;
  float nll = ((t2.x != IGN_) ? (lz0 - xt0) : 0.f) + ((t2.y != IGN_) ? (lz1 - xt1) : 0.f);
  // kl_tb (0 at last row)
  float kl0 = hd ? (Sv0 - dD0 / se0 + __logf(sB0)) : 0.f;
  float kl1 = hd ? (Sv1 - dD1 / se1 + __logf(sB1)) : 0.f;
  // kl_lr: pixel0's right neighbor is pixel1 (register stats, bitwise = its own)
  kl0 += Sv0 - dR0 / se0 + lz1;
  if (hr1) kl1 += Sv1 - dR1 / se1 + __logf(sR1);
  int gp = b * HW_ + p;
  *(float2*)(logZ + gp)   = make_float2(lz0, lz1);
  *(float2*)(S + gp)      = make_float2(Sv0, Sv1);
  *(float2*)(kl_map + gp) = make_float2(kl0, kl1);
  __syncthreads();                       // et/sh init visible
  atomicAdd(&sh[eps_bin(kl0, et)], 1);
  atomicAdd(&sh[eps_bin(kl1, et)], 1);
  __syncthreads();
  if (sh[threadIdx.x]) atomicAdd(&hist[threadIdx.x], sh[threadIdx.x]);
  if (threadIdx.x == 0 && sh[256]) atomicAdd(&hist[256], sh[256]);
  block_reduce_add_w(nll, out, 4);
}

// ---------------- K2: column combine + (block 0) eps selection --------------
// Reads the TRANSPOSED R: lev[0] load is now fully coalesced (320 consecutive
// ints per block instead of 320 stride-1280B latency stalls).
__global__ __launch_bounds__(H_) void k_coldt(const int* __restrict__ Rt, int* __restrict__ dist,
                                              const int* __restrict__ hist, float* __restrict__ eps_sel) {
  int b = blockIdx.x / W_, j = blockIdx.x % W_, tid = threadIdx.x;
  __shared__ int lev[9][H_];
  lev[0][tid] = Rt[(b * W_ + j) * H_ + tid];
  int Ri = lev[0][tid];
  for (int l = 1; l <= 8; ++l) {
    int half = 1 << (l - 1);
    __syncthreads();
    int other = (tid + half < H_) ? lev[l - 1][tid + half] : INF_;
    lev[l][tid] = min(lev[l - 1][tid], other);
  }
  __syncthreads();
  int i0 = tid;
  auto feas = [&](int dd) -> bool {
    int lo = max(0, i0 - dd), hi = min(H_ - 1, i0 + dd);
    int len = hi - lo + 1;
    int l = 31 - __clz(len);
    int m = min(lev[l][lo], lev[l][hi - (1 << l) + 1]);
    return m <= dd;
  };
  int d;
  int hi = min(Ri, 512);                 // d <= R[i0]
  if (!feas(hi)) d = B_ + 1 + H_ + W_;   // no seed in image
  else {
    int lo = 0;
    while (lo < hi) { int mid = (lo + hi) >> 1; if (feas(mid)) hi = mid; else lo = mid + 1; }
    d = lo;
  }
  dist[(b * H_ + i0) * W_ + j] = d;
  // block 0: eps via suffix scan of hist (bins 1..256)
  if (blockIdx.x == 0) {
    __shared__ int g[256];
    __shared__ int bestk;
    if (tid < 256) g[tid] = hist[tid + 1];
    if (tid == 0) bestk = NEPS_ - 1;
    __syncthreads();
    #pragma unroll
    for (int ofs = 1; ofs < 256; ofs <<= 1) {
      int v = 0;
      if (tid < 256) v = g[tid] + ((tid + ofs < 256) ? g[tid + ofs] : 0);
      __syncthreads();
      if (tid < 256) g[tid] = v;
      __syncthreads();
    }
    if (tid < 256 && g[tid] <= 5120) atomicMin(&bestk, tid);
    __syncthreads();
    if (tid == 0) eps_sel[0] = EPS.v[bestk];
  }
}

// ---------------- K3: mask+direction+dterm + in-block sparse CE -------------
__global__ __launch_bounds__(256) void k_maskce(const float* __restrict__ sl, const float* __restrict__ logZ,
                                                const float* __restrict__ S, const float* __restrict__ kl_map,
                                                const int* __restrict__ dist, const float* __restrict__ eps_sel,
                                                float* __restrict__ out) {
  const int nx9[9] = {1,-1,0,0,-1,1,-1,1,0};
  const int ny9[9] = {0,0,-1,1,1,1,-1,-1,0};
  int tid = threadIdx.x;
  int b = blockIdx.z;
  int i0 = blockIdx.y * 16, j0 = blockIdx.x * 16;
  float eps = eps_sel[0];
  __shared__ float kt[18][19];
  __shared__ int   dt_[18][19];
  for (int e = tid; e < 324; e += 256) {
    int r = e / 18, cc = e - r * 18;
    int gi = i0 - 1 + r, gj = j0 - 1 + cc;
    bool in = (gi >= 0 && gi < H_ && gj >= 0 && gj < W_);
    int gidx = (b * H_ + gi) * W_ + gj;
    kt[r][cc]  = in ? kl_map[gidx] : -1e30f;
    dt_[r][cc] = in ? dist[gidx] : 100000;
  }
  __syncthreads();
  int li = tid >> 4, lj = tid & 15;
  bool mask = false;
  #pragma unroll
  for (int dr = 0; dr < 3; ++dr)
    #pragma unroll
    for (int dc = 0; dc < 3; ++dc)
      mask |= (kt[li + dr][lj + dc] > eps);
  int best = INF_, dir = 0;
  #pragma unroll
  for (int k = 0; k < 9; ++k) {
    int r = dt_[li + 1 + nx9[k]][lj + 1 + ny9[k]];
    if (r < best) { best = r; dir = k; }
  }
  bool valid = mask && (dir != 8);
  float acc = valid ? fminf((float)dt_[li + 1][lj + 1], 20.f) * (1.f / 20.f) : 0.f;
  // compact valid pixels into LDS list
  __shared__ int list_[256];
  __shared__ int woff[4];
  __shared__ int tot_s;
  int lane = tid & 63, wid = tid >> 6;
  unsigned long long vote = __ballot(valid);
  if (lane == 0) woff[wid] = __popcll(vote);
  __syncthreads();
  if (tid == 0) {
    int c0 = woff[0], c1 = woff[1], c2 = woff[2], c3 = woff[3];
    tot_s = c0 + c1 + c2 + c3;
    woff[0] = 0; woff[1] = c0; woff[2] = c0 + c1; woff[3] = c0 + c1 + c2;
  }
  __syncthreads();
  if (valid)
    list_[woff[wid] + __popcll(vote & ((1ULL << lane) - 1ULL))] = tid | (min(dir, 7) << 8);
  __syncthreads();
  int cnt = tot_s;
  const float* bse = sl + (size_t)b * CHW_;
  // CE: 8 lanes per entry (lane k = neighbor k)
  for (int base0 = 0; base0 < cnt; base0 += 32) {
    int e = base0 + (tid >> 3), k = tid & 7;
    float ce = 0.f;
    if (e < cnt) {
      int w = list_[e];
      int label = w >> 8, lpos = w & 255;
      int i = i0 + (lpos >> 4), j = j0 + (lpos & 15);
      int pix = i * W_ + j;
      float lzc = logZ[b * HW_ + pix];
      int ic = min(max(i + nx9[k], 0), H_ - 1);
      int jc = min(max(j + ny9[k], 0), W_ - 1);
      int npx = ic * W_ + jc;
      float lzn = logZ[b * HW_ + npx], Sn = S[b * HW_ + npx];
      float dot = 0.f;
      #pragma unroll
      for (int c = 0; c < C_; ++c)
        dot += __expf(bse[c * HW_ + npx] - lzn) * bse[c * HW_ + pix];
      float kv = Sn - dot + lzc;
      float kmax = kv;
      #pragma unroll
      for (int o = 1; o < 8; o <<= 1) kmax = fmaxf(kmax, __shfl_xor(kmax, o));
      float ssum = __expf(kv - kmax);
      #pragma unroll
      for (int o = 1; o < 8; o <<= 1) ssum += __shfl_xor(ssum, o);
      float kll = __shfl(kv, (lane & ~7) | label);
      if (k == 0) ce = kmax + __logf(ssum) - kll;
    }
    acc += ce;
  }
  block_reduce_add_w(acc, out, 4);
}

// ---------------- launch -----------------------------------------------------
extern "C" void kernel_launch(void* const* d_in, const int* in_sizes, int n_in,
                              void* d_out, int out_size, void* d_ws, size_t ws_size,
                              hipStream_t stream) {
  const float* sl  = (const float*)d_in[0];
  const int*   tgt = (const int*)d_in[1];
  float* out = (float*)d_out;

  int*   hist    = (int*)d_ws;                 // 257 ints (zeroed by k_rowdt)
  float* eps_sel = (float*)d_ws + 320;
  float* logZ    = (float*)d_ws + 512;
  float* S       = logZ + NPIX_;
  float* kl_map  = S + NPIX_;
  int*   dist    = (int*)(kl_map + NPIX_);
  int*   Rt      = dist + NPIX_;

  k_rowdt<<<B_ * H_, W_, 0, stream>>>(tgt, Rt, hist, out);
  k_soft<<<NPIX_ / 2 / 256, 256, 0, stream>>>(sl, tgt, logZ, S, kl_map, hist, out);
  k_coldt<<<B_ * W_, H_, 0, stream>>>(Rt, dist, hist, eps_sel);
  k_maskce<<<dim3(W_ / 16, H_ / 16, B_), 256, 0, stream>>>(sl, logZ, S, kl_map, dist, eps_sel, out);
}